// Round 7
// baseline (349.676 us; speedup 1.0000x reference)
//
#include <hip/hip_runtime.h>
#include <hip/hip_bf16.h>
#include <math.h>

// ---------------- problem constants ----------------
#define BATCH   8
#define SEQL    8192
#define DOUTD   512
#define DHID    256
#define MTOT    (BATCH*SEQL)      // 65536
#define CHUNKS  128               // scan chunks per sequence
#define CHUNKLN 64                // SEQL/CHUNKS
#define SQUAR   6                 // log2(CHUNKLN)

typedef __bf16 bh;
typedef __bf16 bh8 __attribute__((ext_vector_type(8)));
typedef float  f32x4 __attribute__((ext_vector_type(4)));

// ---------------- x fp32 -> bf16 ----------------
__global__ void conv_x_kernel(const float4* __restrict__ x, bh* __restrict__ xh) {
    long i = (long)blockIdx.x * 256 + threadIdx.x;   // each thread: 8 floats
    float4 a = x[2 * i], c = x[2 * i + 1];
    bh8 o;
    o[0] = (bh)a.x; o[1] = (bh)a.y; o[2] = (bh)a.z; o[3] = (bh)a.w;
    o[4] = (bh)c.x; o[5] = (bh)c.y; o[6] = (bh)c.z; o[7] = (bh)c.w;
    *(bh8*)(xh + i * 8) = o;
}

// ---------------- small precompute: lam, lam^S, bB, bD ----------------
__global__ void prep0_kernel(const float* __restrict__ nu_log, const float* __restrict__ theta_log,
                             const float* __restrict__ gamma_log, const float* __restrict__ Bre,
                             const float* __restrict__ Bim, const float* __restrict__ bvec,
                             const float* __restrict__ Dvec,
                             float* lamRe, float* lamIm, float* lamSRe, float* lamSIm,
                             float* gamma, float* bB, float* bD) {
    int t = threadIdx.x;
    if (t < 512) bD[t] = bvec[t] * Dvec[t];
    if (t < 256) {
        float nu = expf(nu_log[t]);
        float th = expf(theta_log[t]);
        float mag = expf(-nu);
        float lr = mag * cosf(th), li = mag * sinf(th);
        lamRe[t] = lr; lamIm[t] = li;
        float pr = lr, pi = li;
        for (int s = 0; s < SQUAR; ++s) { float nr = pr*pr - pi*pi, ni = 2.f*pr*pi; pr = nr; pi = ni; }
        lamSRe[t] = pr; lamSIm[t] = pi;
        float g = expf(gamma_log[t]);
        gamma[t] = g;
        float sre = 0.f, sim = 0.f;
        for (int k = 0; k < 512; ++k) {
            float bk = bvec[k];
            sre += bk * Bre[t * 512 + k];
            sim += bk * Bim[t * 512 + k];
        }
        bB[t] = sre * g; bB[t + 256] = sim * g;
    }
}

// WBt[c][j] (bf16, [512][512]) = sum_k W[j,k]*B_{re/im}[c mod 256, k] * gamma
__global__ void prepWB_kernel(const float* __restrict__ W, const float* __restrict__ Bre,
                              const float* __restrict__ Bim, const float* __restrict__ gamma,
                              bh* __restrict__ WBt) {
    int e = blockIdx.x * 256 + threadIdx.x;   // over 512*512
    int c = e >> 9, j = e & 511;
    const float* Bp = (c < 256) ? (Bre + c * 512) : (Bim + (c - 256) * 512);
    float g = gamma[c & 255];
    float s = 0.f;
    for (int k = 0; k < 512; ++k) s += W[j * 512 + k] * Bp[k];
    WBt[e] = (bh)(s * g);
}

// WcT[c][k'] (bf16, [512][1024]): k'<256: Cre[c][k']; <512: -Cim[c][k'-256]; else W[k'-512][c]*D[c]
__global__ void prepWC_kernel(const float* __restrict__ Cre, const float* __restrict__ Cim,
                              const float* __restrict__ W, const float* __restrict__ Dvec,
                              bh* __restrict__ WcT) {
    int e = blockIdx.x * 256 + threadIdx.x;   // over 512*1024
    int c = e >> 10, kp = e & 1023;
    float v;
    if (kp < 256)       v = Cre[c * 256 + kp];
    else if (kp < 512)  v = -Cim[c * 256 + (kp - 256)];
    else                v = W[(kp - 512) * 512 + c] * Dvec[c];
    WcT[e] = (bh)v;
}

// ============ bf16 MFMA GEMM: 256x256 tile, BK=64, 8-phase schedule ============
// T3+T4: 8 phases / 2 K-tiles per iter; counted vmcnt(2) ONLY at phases 4/8
// (before the close-barrier, protecting the next buffer's block-wide reads;
//  tail iterations drop to vmcnt(0) by wave-uniform branch).
// T2: XOR-slot swizzle slot' = slot ^ (row&7) on 128B rows; applied as
//     inverse-swizzled GLOBAL source + swizzled ds_read (linear gload_lds dest,
//     rule 21). Kills the 16-way read conflict (2.5e7 @ r6).
// T5: setprio(1) around each 16-MFMA quadrant cluster.
// 8 waves = 2(M) x 4(N); per-wave output 128x64 = acc[8][4] f32x4.
// MFMA input k-permutation irrelevant (A/B frags share the (rsub,g)->k map).

#define MMAQ(mh, nh) \
  _Pragma("unroll") for (int ks = 0; ks < 2; ++ks) \
  _Pragma("unroll") for (int mi = 0; mi < 4; ++mi) \
  _Pragma("unroll") for (int ni = 0; ni < 2; ++ni) \
    acc[(mh)*4+mi][(nh)*2+ni] = __builtin_amdgcn_mfma_f32_16x16x32_bf16( \
        afr[mi*2+ks], bfr[((nh)*2+ni)*2+ks], acc[(mh)*4+mi][(nh)*2+ni], 0, 0, 0);

#define PH_MMA(mh, nh) \
  __builtin_amdgcn_sched_barrier(0); \
  __builtin_amdgcn_s_barrier(); \
  __builtin_amdgcn_sched_barrier(0); \
  __builtin_amdgcn_s_setprio(1); \
  MMAQ(mh, nh) \
  __builtin_amdgcn_s_setprio(0); \
  __builtin_amdgcn_sched_barrier(0); \
  __builtin_amdgcn_s_barrier();

template<int KTOT, bool SPLIT_A, bool OUT_F32>
__global__ __launch_bounds__(512, 2)
void gemm_kernel(const bh* __restrict__ A0, const bh* __restrict__ A1,
                 const bh* __restrict__ Bw, const float* __restrict__ bias,
                 float* __restrict__ outF, bh* __restrict__ outH) {
    __shared__ alignas(16) bh lds[65536];    // 128KB: buf[2] x { A[256][64] | B[256][64] }
    const int tid = threadIdx.x;
    const int l = tid & 63, w = tid >> 6;
    const int wm = w >> 2, wn = w & 3;                 // 2 x 4 waves
    const int bid = blockIdx.x, nwg = gridDim.x;       // nwg % 8 == 0 (512)
    const int swz = (bid & 7) * (nwg >> 3) + (bid >> 3);
    const int rowBase = (swz >> 1) * 256;              // 256 row bands
    const int colBase = (swz & 1) * 256;               // 2 col tiles
    const int rsub = l & 15, g = l >> 4;
    const int r7 = rsub & 7;
    const int sl0 = ((0 + g) ^ r7) * 8;                // ks=0 swizzled slot (elems)
    const int sl1 = ((4 + g) ^ r7) * 8;                // ks=1
    // staging thread map: row_in_half = j*64 + (tid>>3); linear LDS slot = tid&7;
    // inverse-swizzled global slot:
    const int st_r  = tid >> 3;                        // 0..63
    const int st_sl = ((tid & 7) ^ (st_r & 7)) * 8;    // global col elems offset
    const int st_ld = (tid & 7) * 8;                   // linear LDS slot elems

    f32x4 acc[8][4] = {};
    bh8 afr[8];   // 4 m-frags x 2 ks (reused for m-half 0/1)
    bh8 bfr[8];   // 4 n-frags x 2 ks (all live)

    const int NT  = KTOT / 64;
    const int NIT = NT / 2;

    auto stageA = [&](int t, int half, int bufsel) {   // 2 global_load_lds
        const int k0 = t * 64;
        const bh* As = A0; int kk = k0;
        if (SPLIT_A && k0 >= 512) { As = A1; kk = k0 - 512; }
        bh* lb = &lds[bufsel * 32768];
#pragma unroll
        for (int j = 0; j < 2; ++j) {
            const int rt = half * 128 + j * 64 + st_r;           // row in tile
            const bh* ga = As + (size_t)(rowBase + rt) * 512 + kk + st_sl;
            __builtin_amdgcn_global_load_lds(
                (const __attribute__((address_space(1))) void*)ga,
                (__attribute__((address_space(3))) void*)&lb[rt * 64 + st_ld], 16, 0, 0);
        }
    };
    auto stageB = [&](int t, int half, int bufsel) {
        const int k0 = t * 64;
        bh* lb = &lds[bufsel * 32768 + 16384];
#pragma unroll
        for (int j = 0; j < 2; ++j) {
            const int rt = half * 128 + j * 64 + st_r;
            const bh* gb = Bw + (size_t)(colBase + rt) * KTOT + k0 + st_sl;
            __builtin_amdgcn_global_load_lds(
                (const __attribute__((address_space(1))) void*)gb,
                (__attribute__((address_space(3))) void*)&lb[rt * 64 + st_ld], 16, 0, 0);
        }
    };
    auto dsA = [&](int mh, int bufsel) {               // 8 x ds_read_b128
        const bh* lb = &lds[bufsel * 32768];
#pragma unroll
        for (int mi = 0; mi < 4; ++mi) {
            const int row = wm * 128 + (mh * 4 + mi) * 16 + rsub;
            afr[mi * 2 + 0] = *(const bh8*)&lb[row * 64 + sl0];
            afr[mi * 2 + 1] = *(const bh8*)&lb[row * 64 + sl1];
        }
    };
    auto dsB = [&](int nh, int bufsel) {               // 4 x ds_read_b128
        const bh* lb = &lds[bufsel * 32768 + 16384];
#pragma unroll
        for (int ni = 0; ni < 2; ++ni) {
            const int row = wn * 64 + (nh * 2 + ni) * 16 + rsub;
            bfr[(nh * 2 + ni) * 2 + 0] = *(const bh8*)&lb[row * 64 + sl0];
            bfr[(nh * 2 + ni) * 2 + 1] = *(const bh8*)&lb[row * 64 + sl1];
        }
    };

    // ---- prologue: tile0 full + A0(tile1); 10 loads; wait tile0, keep 2 in flight
    stageA(0, 0, 0); stageA(0, 1, 0); stageB(0, 0, 0); stageB(0, 1, 0);
    stageA(1, 0, 1);
    __builtin_amdgcn_sched_barrier(0);
    asm volatile("s_waitcnt vmcnt(2)" ::: "memory");
    __builtin_amdgcn_s_barrier();

    for (int i = 0; i < NIT; ++i) {
        const int t0 = 2 * i, t1 = 2 * i + 1;
        // ---- phase 1 [buf0]: Q(0,0); reads afr(mh0)+bfr(nh0); stage A1(t1)->buf1
        dsA(0, 0); dsB(0, 0);
        stageA(t1, 1, 1);
        PH_MMA(0, 0)
        // ---- phase 2: Q(0,1); reads bfr(nh1); stage B0(t1)->buf1
        dsB(1, 0);
        stageB(t1, 0, 1);
        PH_MMA(0, 1)
        // ---- phase 3: Q(1,1); reads afr(mh1); stage B1(t1)->buf1
        dsA(1, 0);
        stageB(t1, 1, 1);
        PH_MMA(1, 1)
        // ---- phase 4: Q(1,0); no reads; stage A0(t0+2)->buf0; vmcnt before close
        if (t0 + 2 < NT) stageA(t0 + 2, 0, 0);
        __builtin_amdgcn_sched_barrier(0);
        __builtin_amdgcn_s_barrier();
        __builtin_amdgcn_sched_barrier(0);
        __builtin_amdgcn_s_setprio(1);
        MMAQ(1, 0)
        __builtin_amdgcn_s_setprio(0);
        __builtin_amdgcn_sched_barrier(0);
        if (t0 + 2 < NT) { asm volatile("s_waitcnt vmcnt(2)" ::: "memory"); }
        else             { asm volatile("s_waitcnt vmcnt(0)" ::: "memory"); }
        __builtin_amdgcn_s_barrier();    // close ph4: buf1 (t1) fully landed for ph5-7
        // ---- phase 5 [buf1]: Q(0,0); stage A1(t0+2)->buf0
        dsA(0, 1); dsB(0, 1);
        if (t0 + 2 < NT) stageA(t0 + 2, 1, 0);
        PH_MMA(0, 0)
        // ---- phase 6: Q(0,1); stage B0(t0+2)->buf0
        dsB(1, 1);
        if (t0 + 2 < NT) stageB(t0 + 2, 0, 0);
        PH_MMA(0, 1)
        // ---- phase 7: Q(1,1); stage B1(t0+2)->buf0
        dsA(1, 1);
        if (t0 + 2 < NT) stageB(t0 + 2, 1, 0);
        PH_MMA(1, 1)
        // ---- phase 8: Q(1,0); stage A0(t1+2)->buf1; vmcnt before close
        if (t1 + 2 < NT) stageA(t1 + 2, 0, 1);
        __builtin_amdgcn_sched_barrier(0);
        __builtin_amdgcn_s_barrier();
        __builtin_amdgcn_sched_barrier(0);
        __builtin_amdgcn_s_setprio(1);
        MMAQ(1, 0)
        __builtin_amdgcn_s_setprio(0);
        __builtin_amdgcn_sched_barrier(0);
        if (t1 + 2 < NT) { asm volatile("s_waitcnt vmcnt(2)" ::: "memory"); }
        else             { asm volatile("s_waitcnt vmcnt(0)" ::: "memory"); }
        __builtin_amdgcn_s_barrier();    // close ph8: buf0 (t0+2) landed for next ph1-3
    }

    // ---- epilogue
#pragma unroll
    for (int m = 0; m < 8; ++m)
#pragma unroll
        for (int j = 0; j < 4; ++j) {
            const int row = rowBase + wm * 128 + m * 16 + g * 4 + j;
#pragma unroll
            for (int n = 0; n < 4; ++n) {
                const int col = colBase + wn * 64 + n * 16 + rsub;
                float v = acc[m][n][j] + bias[col];
                if (OUT_F32) outF[(size_t)row * 512 + col] = v;
                else         outH[(size_t)row * 512 + col] = (bh)v;
            }
        }
}

// ---------------- chunked complex scan (3 passes) ----------------
__global__ void scan1_kernel(const bh* __restrict__ Bu, const float* __restrict__ lamRe,
                             const float* __restrict__ lamIm, float* __restrict__ carRe,
                             float* __restrict__ carIm) {
    int b = blockIdx.x >> 7, c = blockIdx.x & (CHUNKS - 1);
    int n = threadIdx.x;
    float lr = lamRe[n], li = lamIm[n];
    float hr = 0.f, hi = 0.f;
    const bh* p = Bu + ((size_t)(b * SEQL + c * CHUNKLN)) * 512;
    for (int i = 0; i < CHUNKLN; ++i) {
        float br = (float)p[n], bi = (float)p[n + 256];
        float nr = lr * hr - li * hi + br;
        float ni = lr * hi + li * hr + bi;
        hr = nr; hi = ni; p += 512;
    }
    carRe[(size_t)blockIdx.x * 256 + n] = hr;
    carIm[(size_t)blockIdx.x * 256 + n] = hi;
}

__global__ void scan2_kernel(const float* __restrict__ carRe, const float* __restrict__ carIm,
                             const float* __restrict__ lamSRe, const float* __restrict__ lamSIm,
                             float* __restrict__ iniRe, float* __restrict__ iniIm) {
    int b = blockIdx.x, n = threadIdx.x;
    float lr = lamSRe[n], li = lamSIm[n];
    float hr = 0.f, hi = 0.f;
    for (int c = 0; c < CHUNKS; ++c) {
        size_t idx = ((size_t)b * CHUNKS + c) * 256 + n;
        iniRe[idx] = hr; iniIm[idx] = hi;
        float cr = carRe[idx], ci = carIm[idx];
        float nr = lr * hr - li * hi + cr;
        float ni = lr * hi + li * hr + ci;
        hr = nr; hi = ni;
    }
}

// pass 3: recompute local scan with carry-in, write h (bf16, in-place over Bu) + tail (planar)
__global__ void scan3_kernel(bh* __restrict__ Bu, const float* __restrict__ lamRe,
                             const float* __restrict__ lamIm, const float* __restrict__ iniRe,
                             const float* __restrict__ iniIm, float* __restrict__ outTail,
                             int tailN) {
    int b = blockIdx.x >> 7, c = blockIdx.x & (CHUNKS - 1);
    int n = threadIdx.x;
    float lr = lamRe[n], li = lamIm[n];
    size_t idx = (size_t)blockIdx.x * 256 + n;
    float hr = iniRe[idx], hi = iniIm[idx];
    bh* p = Bu + ((size_t)(b * SEQL + c * CHUNKLN)) * 512;
    for (int i = 0; i < CHUNKLN; ++i) {
        float br = (float)p[n], bi = (float)p[n + 256];
        float nr = lr * hr - li * hi + br;
        float ni = lr * hi + li * hr + bi;
        hr = nr; hi = ni;
        p[n] = (bh)hr; p[n + 256] = (bh)hi;
        p += 512;
    }
    if (c == CHUNKS - 1) {                 // h[:, L-1]
        if (tailN >= 4096) {               // planar: all re, then all im
            outTail[b * 256 + n]        = hr;
            outTail[2048 + b * 256 + n] = hi;
        } else {
            outTail[b * 256 + n] = hr;
        }
    }
}

// ---------------- launch ----------------
extern "C" void kernel_launch(void* const* d_in, const int* in_sizes, int n_in,
                              void* d_out, int out_size, void* d_ws, size_t ws_size,
                              hipStream_t stream) {
    const float* x        = (const float*)d_in[0];
    const float* W        = (const float*)d_in[1];
    const float* bvec     = (const float*)d_in[2];
    const float* nu_log   = (const float*)d_in[3];
    const float* theta_lg = (const float*)d_in[4];
    const float* gamma_lg = (const float*)d_in[5];
    const float* Bre      = (const float*)d_in[6];
    const float* Bim      = (const float*)d_in[7];
    const float* Cre      = (const float*)d_in[8];
    const float* Cim      = (const float*)d_in[9];
    const float* Dvec     = (const float*)d_in[10];

    char* ws = (char*)d_ws;
    bh* xh   = (bh*)(ws);                                   // 64 MB
    bh* bu   = (bh*)(ws + 67108864);                        // 64 MB (becomes h in-place)
    bh* wbt  = (bh*)(ws + 134217728);                       // 512 KB
    bh* wct  = (bh*)(ws + 134217728 + 524288);              // 1 MB
    float* sm = (float*)(ws + 134217728 + 524288 + 1048576);
    float* bB = sm;               // 512
    float* bD = sm + 512;         // 512
    float* lamRe  = sm + 1024;    // 256
    float* lamIm  = sm + 1280;
    float* lamSRe = sm + 1536;
    float* lamSIm = sm + 1792;
    float* gamma  = sm + 2048;    // 256
    float* carRe  = sm + 2304;                 // 8*128*256 each
    float* carIm  = carRe + (size_t)BATCH * CHUNKS * 256;
    float* iniRe  = carIm + (size_t)BATCH * CHUNKS * 256;
    float* iniIm  = iniRe + (size_t)BATCH * CHUNKS * 256;

    float* outF    = (float*)d_out;
    float* outTail = outF + (size_t)MTOT * DOUTD;
    int tailN = out_size - MTOT * DOUTD;       // 4096 (float view) or 2048

    conv_x_kernel<<<16384, 256, 0, stream>>>((const float4*)x, xh);
    prep0_kernel<<<1, 512, 0, stream>>>(nu_log, theta_lg, gamma_lg, Bre, Bim, bvec, Dvec,
                                        lamRe, lamIm, lamSRe, lamSIm, gamma, bB, bD);
    prepWB_kernel<<<1024, 256, 0, stream>>>(W, Bre, Bim, gamma, wbt);
    prepWC_kernel<<<2048, 256, 0, stream>>>(Cre, Cim, W, Dvec, wct);

    gemm_kernel<512, false, false><<<512, 512, 0, stream>>>(xh, nullptr, wbt, bB, nullptr, bu);

    scan1_kernel<<<BATCH * CHUNKS, 256, 0, stream>>>(bu, lamRe, lamIm, carRe, carIm);
    scan2_kernel<<<BATCH, 256, 0, stream>>>(carRe, carIm, lamSRe, lamSIm, iniRe, iniIm);
    scan3_kernel<<<BATCH * CHUNKS, 256, 0, stream>>>(bu, lamRe, lamIm, iniRe, iniIm, outTail, tailN);

    gemm_kernel<1024, true, true><<<512, 512, 0, stream>>>(bu, xh, wct, bD, outF, nullptr);
}

// Round 8
// 291.300 us; speedup vs baseline: 1.2004x; 1.2004x over previous
//
#include <hip/hip_runtime.h>
#include <hip/hip_bf16.h>
#include <math.h>

// ---------------- problem constants ----------------
#define BATCH   8
#define SEQL    8192
#define DOUTD   512
#define DHID    256
#define MTOT    (BATCH*SEQL)      // 65536
#define CHUNKS  128               // scan chunks per sequence
#define CHUNKLN 64                // SEQL/CHUNKS
#define SQUAR   6                 // log2(CHUNKLN)

typedef __bf16 bh;
typedef __bf16 bh8 __attribute__((ext_vector_type(8)));
typedef float  f32x4 __attribute__((ext_vector_type(4)));

// ---------------- x fp32 -> bf16 ----------------
__global__ void conv_x_kernel(const float4* __restrict__ x, bh* __restrict__ xh) {
    long i = (long)blockIdx.x * 256 + threadIdx.x;   // each thread: 8 floats
    float4 a = x[2 * i], c = x[2 * i + 1];
    bh8 o;
    o[0] = (bh)a.x; o[1] = (bh)a.y; o[2] = (bh)a.z; o[3] = (bh)a.w;
    o[4] = (bh)c.x; o[5] = (bh)c.y; o[6] = (bh)c.z; o[7] = (bh)c.w;
    *(bh8*)(xh + i * 8) = o;
}

// ---------------- small precompute: lam, lam^S, bB, bD ----------------
__global__ void prep0_kernel(const float* __restrict__ nu_log, const float* __restrict__ theta_log,
                             const float* __restrict__ gamma_log, const float* __restrict__ Bre,
                             const float* __restrict__ Bim, const float* __restrict__ bvec,
                             const float* __restrict__ Dvec,
                             float* lamRe, float* lamIm, float* lamSRe, float* lamSIm,
                             float* gamma, float* bB, float* bD) {
    int t = threadIdx.x;
    if (t < 512) bD[t] = bvec[t] * Dvec[t];
    if (t < 256) {
        float nu = expf(nu_log[t]);
        float th = expf(theta_log[t]);
        float mag = expf(-nu);
        float lr = mag * cosf(th), li = mag * sinf(th);
        lamRe[t] = lr; lamIm[t] = li;
        float pr = lr, pi = li;
        for (int s = 0; s < SQUAR; ++s) { float nr = pr*pr - pi*pi, ni = 2.f*pr*pi; pr = nr; pi = ni; }
        lamSRe[t] = pr; lamSIm[t] = pi;
        float g = expf(gamma_log[t]);
        gamma[t] = g;
        float sre = 0.f, sim = 0.f;
        for (int k = 0; k < 512; ++k) {
            float bk = bvec[k];
            sre += bk * Bre[t * 512 + k];
            sim += bk * Bim[t * 512 + k];
        }
        bB[t] = sre * g; bB[t + 256] = sim * g;
    }
}

// ---------------- W transpose (coalesced, 64x64 LDS tiles) ----------------
__global__ void transposeW_kernel(const float* __restrict__ W, float* __restrict__ Wt) {
    __shared__ float t[64][65];
    const int bx = blockIdx.x & 7, by = blockIdx.x >> 3;   // 8x8 tiles of 64x64
    const int r0 = by * 64, c0 = bx * 64;
    const int tr = threadIdx.x >> 4;          // 0..15
    const int tc = (threadIdx.x & 15) * 4;    // float4 col offset
#pragma unroll
    for (int rr = 0; rr < 64; rr += 16) {
        float4 v = *(const float4*)&W[(size_t)(r0 + tr + rr) * 512 + c0 + tc];
        t[tr + rr][tc + 0] = v.x; t[tr + rr][tc + 1] = v.y;
        t[tr + rr][tc + 2] = v.z; t[tr + rr][tc + 3] = v.w;
    }
    __syncthreads();
#pragma unroll
    for (int rr = 0; rr < 64; rr += 16) {
        const int orow = tr + rr;             // col index in W
        float4 o;
        o.x = t[tc + 0][orow]; o.y = t[tc + 1][orow];
        o.z = t[tc + 2][orow]; o.w = t[tc + 3][orow];
        *(float4*)&Wt[(size_t)(c0 + orow) * 512 + r0 + tc] = o;
    }
}

// WBt[c][j] = gamma[c&255] * sum_k W[j][k]*Bsel[c][k]; coalesced via Wt[k][j].
// 128 blocks x 4 c-rows; B' rows staged in LDS; float2 Wt loads.
__global__ void prepWB_kernel(const float* __restrict__ Wt, const float* __restrict__ Bre,
                              const float* __restrict__ Bim, const float* __restrict__ gamma,
                              bh* __restrict__ WBt) {
    __shared__ float bsh[4][512];
    const int c0 = blockIdx.x * 4;
    const int tid = threadIdx.x;
    for (int i = tid; i < 2048; i += 256) {
        int ci = i >> 9, k = i & 511;
        int c = c0 + ci;
        float v = (c < 256) ? Bre[(size_t)c * 512 + k] : Bim[(size_t)(c - 256) * 512 + k];
        bsh[ci][k] = v * gamma[c & 255];
    }
    __syncthreads();
    const int j = tid * 2;
    float a0[4] = {}, a1[4] = {};
    for (int k = 0; k < 512; ++k) {
        float2 wv = *(const float2*)&Wt[(size_t)k * 512 + j];
#pragma unroll
        for (int ci = 0; ci < 4; ++ci) {
            float b = bsh[ci][k];
            a0[ci] += wv.x * b;
            a1[ci] += wv.y * b;
        }
    }
#pragma unroll
    for (int ci = 0; ci < 4; ++ci) {
        WBt[(size_t)(c0 + ci) * 512 + j]     = (bh)a0[ci];
        WBt[(size_t)(c0 + ci) * 512 + j + 1] = (bh)a1[ci];
    }
}

// WcT[c][k'] : k'<256 Cre; <512 -Cim; else Wt[c][k'-512]*D[c]  (all coalesced)
__global__ void prepWC_kernel(const float* __restrict__ Cre, const float* __restrict__ Cim,
                              const float* __restrict__ Wt, const float* __restrict__ Dvec,
                              bh* __restrict__ WcT) {
    int e = blockIdx.x * 256 + threadIdx.x;   // over 512*1024
    int c = e >> 10, kp = e & 1023;
    float v;
    if (kp < 256)       v = Cre[c * 256 + kp];
    else if (kp < 512)  v = -Cim[c * 256 + (kp - 256)];
    else                v = Wt[(size_t)c * 512 + (kp - 512)] * Dvec[c];
    WcT[e] = (bh)v;
}

// ============ bf16 MFMA GEMM: 256x256 tile, BK=64, 8-phase schedule ============
// T3+T4+T2+T5 (r7-verified: bank conflicts 0). r8 changes: bfr[8]->bfr[4]
// (dsB(0) reloaded at phases 4/8) to kill register spill; sched_barrier(0)
// dropped everywhere except after vmcnt asm (m141: over-pinning regresses).

#define MMAQ(mh, nh) \
  _Pragma("unroll") for (int ks = 0; ks < 2; ++ks) \
  _Pragma("unroll") for (int mi = 0; mi < 4; ++mi) \
  _Pragma("unroll") for (int ni = 0; ni < 2; ++ni) \
    acc[(mh)*4+mi][(nh)*2+ni] = __builtin_amdgcn_mfma_f32_16x16x32_bf16( \
        afr[mi*2+ks], bfr[ni*2+ks], acc[(mh)*4+mi][(nh)*2+ni], 0, 0, 0);

#define PH_MMA(mh, nh) \
  __builtin_amdgcn_s_barrier(); \
  __builtin_amdgcn_s_setprio(1); \
  MMAQ(mh, nh) \
  __builtin_amdgcn_s_setprio(0); \
  __builtin_amdgcn_s_barrier();

template<int KTOT, bool SPLIT_A, bool OUT_F32>
__global__ __launch_bounds__(512, 2)
void gemm_kernel(const bh* __restrict__ A0, const bh* __restrict__ A1,
                 const bh* __restrict__ Bw, const float* __restrict__ bias,
                 float* __restrict__ outF, bh* __restrict__ outH) {
    __shared__ alignas(16) bh lds[65536];    // 128KB: buf[2] x { A[256][64] | B[256][64] }
    const int tid = threadIdx.x;
    const int l = tid & 63, w = tid >> 6;
    const int wm = w >> 2, wn = w & 3;                 // 2 x 4 waves
    const int bid = blockIdx.x, nwg = gridDim.x;       // nwg % 8 == 0 (512)
    const int swz = (bid & 7) * (nwg >> 3) + (bid >> 3);
    const int rowBase = (swz >> 1) * 256;              // 256 row bands
    const int colBase = (swz & 1) * 256;               // 2 col tiles
    const int rsub = l & 15, g = l >> 4;
    const int r7 = rsub & 7;
    const int sl0 = ((0 + g) ^ r7) * 8;                // ks=0 swizzled slot (elems)
    const int sl1 = ((4 + g) ^ r7) * 8;                // ks=1
    const int st_r  = tid >> 3;                        // 0..63
    const int st_sl = ((tid & 7) ^ (st_r & 7)) * 8;    // inverse-swizzled global slot
    const int st_ld = (tid & 7) * 8;                   // linear LDS slot

    f32x4 acc[8][4] = {};
    bh8 afr[8];   // 4 m-frags x 2 ks
    bh8 bfr[4];   // 2 n-frags x 2 ks (per current nh only)

    const int NT  = KTOT / 64;
    const int NIT = NT / 2;

    auto stageA = [&](int t, int half, int bufsel) {
        const int k0 = t * 64;
        const bh* As = A0; int kk = k0;
        if (SPLIT_A && k0 >= 512) { As = A1; kk = k0 - 512; }
        bh* lb = &lds[bufsel * 32768];
#pragma unroll
        for (int j = 0; j < 2; ++j) {
            const int rt = half * 128 + j * 64 + st_r;
            const bh* ga = As + (size_t)(rowBase + rt) * 512 + kk + st_sl;
            __builtin_amdgcn_global_load_lds(
                (const __attribute__((address_space(1))) void*)ga,
                (__attribute__((address_space(3))) void*)&lb[rt * 64 + st_ld], 16, 0, 0);
        }
    };
    auto stageB = [&](int t, int half, int bufsel) {
        const int k0 = t * 64;
        bh* lb = &lds[bufsel * 32768 + 16384];
#pragma unroll
        for (int j = 0; j < 2; ++j) {
            const int rt = half * 128 + j * 64 + st_r;
            const bh* gb = Bw + (size_t)(colBase + rt) * KTOT + k0 + st_sl;
            __builtin_amdgcn_global_load_lds(
                (const __attribute__((address_space(1))) void*)gb,
                (__attribute__((address_space(3))) void*)&lb[rt * 64 + st_ld], 16, 0, 0);
        }
    };
    auto dsA = [&](int mh, int bufsel) {               // 8 x ds_read_b128
        const bh* lb = &lds[bufsel * 32768];
#pragma unroll
        for (int mi = 0; mi < 4; ++mi) {
            const int row = wm * 128 + (mh * 4 + mi) * 16 + rsub;
            afr[mi * 2 + 0] = *(const bh8*)&lb[row * 64 + sl0];
            afr[mi * 2 + 1] = *(const bh8*)&lb[row * 64 + sl1];
        }
    };
    auto dsB = [&](int nh, int bufsel) {               // 4 x ds_read_b128
        const bh* lb = &lds[bufsel * 32768 + 16384];
#pragma unroll
        for (int ni = 0; ni < 2; ++ni) {
            const int row = wn * 64 + (nh * 2 + ni) * 16 + rsub;
            bfr[ni * 2 + 0] = *(const bh8*)&lb[row * 64 + sl0];
            bfr[ni * 2 + 1] = *(const bh8*)&lb[row * 64 + sl1];
        }
    };

    // ---- prologue: tile0 full + A-half0(tile1); wait tile0, keep 2 in flight
    stageA(0, 0, 0); stageA(0, 1, 0); stageB(0, 0, 0); stageB(0, 1, 0);
    stageA(1, 0, 1);
    asm volatile("s_waitcnt vmcnt(2)" ::: "memory");
    __builtin_amdgcn_sched_barrier(0);
    __builtin_amdgcn_s_barrier();

    for (int i = 0; i < NIT; ++i) {
        const int t0 = 2 * i, t1 = 2 * i + 1;
        // ph1 [buf0]: Q(0,0)
        dsA(0, 0); dsB(0, 0);
        stageA(t1, 1, 1);
        PH_MMA(0, 0)
        // ph2: Q(0,1)
        dsB(1, 0);
        stageB(t1, 0, 1);
        PH_MMA(0, 1)
        // ph3: Q(1,1)
        dsA(1, 0);
        stageB(t1, 1, 1);
        PH_MMA(1, 1)
        // ph4: Q(1,0); reload B(0); vmcnt before close
        dsB(0, 0);
        if (t0 + 2 < NT) stageA(t0 + 2, 0, 0);
        __builtin_amdgcn_s_barrier();
        __builtin_amdgcn_s_setprio(1);
        MMAQ(1, 0)
        __builtin_amdgcn_s_setprio(0);
        if (t0 + 2 < NT) { asm volatile("s_waitcnt vmcnt(2)" ::: "memory"); }
        else             { asm volatile("s_waitcnt vmcnt(0)" ::: "memory"); }
        __builtin_amdgcn_sched_barrier(0);
        __builtin_amdgcn_s_barrier();    // buf1 (t1) fully landed for ph5-8
        // ph5 [buf1]: Q(0,0)
        dsA(0, 1); dsB(0, 1);
        if (t0 + 2 < NT) stageA(t0 + 2, 1, 0);
        PH_MMA(0, 0)
        // ph6: Q(0,1)
        dsB(1, 1);
        if (t0 + 2 < NT) stageB(t0 + 2, 0, 0);
        PH_MMA(0, 1)
        // ph7: Q(1,1)
        dsA(1, 1);
        if (t0 + 2 < NT) stageB(t0 + 2, 1, 0);
        PH_MMA(1, 1)
        // ph8: Q(1,0); reload B(0); vmcnt before close
        dsB(0, 1);
        if (t1 + 2 < NT) stageA(t1 + 2, 0, 1);
        __builtin_amdgcn_s_barrier();
        __builtin_amdgcn_s_setprio(1);
        MMAQ(1, 0)
        __builtin_amdgcn_s_setprio(0);
        if (t1 + 2 < NT) { asm volatile("s_waitcnt vmcnt(2)" ::: "memory"); }
        else             { asm volatile("s_waitcnt vmcnt(0)" ::: "memory"); }
        __builtin_amdgcn_sched_barrier(0);
        __builtin_amdgcn_s_barrier();    // buf0 (t0+2) landed for next ph1-3
    }

    // ---- epilogue
#pragma unroll
    for (int m = 0; m < 8; ++m)
#pragma unroll
        for (int j = 0; j < 4; ++j) {
            const int row = rowBase + wm * 128 + m * 16 + g * 4 + j;
#pragma unroll
            for (int n = 0; n < 4; ++n) {
                const int col = colBase + wn * 64 + n * 16 + rsub;
                float v = acc[m][n][j] + bias[col];
                if (OUT_F32) outF[(size_t)row * 512 + col] = v;
                else         outH[(size_t)row * 512 + col] = (bh)v;
            }
        }
}

// ---------------- chunked complex scan (3 passes) ----------------
__global__ void scan1_kernel(const bh* __restrict__ Bu, const float* __restrict__ lamRe,
                             const float* __restrict__ lamIm, float* __restrict__ carRe,
                             float* __restrict__ carIm) {
    int b = blockIdx.x >> 7, c = blockIdx.x & (CHUNKS - 1);
    int n = threadIdx.x;
    float lr = lamRe[n], li = lamIm[n];
    float hr = 0.f, hi = 0.f;
    const bh* p = Bu + ((size_t)(b * SEQL + c * CHUNKLN)) * 512;
    for (int i = 0; i < CHUNKLN; ++i) {
        float br = (float)p[n], bi = (float)p[n + 256];
        float nr = lr * hr - li * hi + br;
        float ni = lr * hi + li * hr + bi;
        hr = nr; hi = ni; p += 512;
    }
    carRe[(size_t)blockIdx.x * 256 + n] = hr;
    carIm[(size_t)blockIdx.x * 256 + n] = hi;
}

__global__ void scan2_kernel(const float* __restrict__ carRe, const float* __restrict__ carIm,
                             const float* __restrict__ lamSRe, const float* __restrict__ lamSIm,
                             float* __restrict__ iniRe, float* __restrict__ iniIm) {
    int b = blockIdx.x, n = threadIdx.x;
    float lr = lamSRe[n], li = lamSIm[n];
    float hr = 0.f, hi = 0.f;
    for (int c = 0; c < CHUNKS; ++c) {
        size_t idx = ((size_t)b * CHUNKS + c) * 256 + n;
        iniRe[idx] = hr; iniIm[idx] = hi;
        float cr = carRe[idx], ci = carIm[idx];
        float nr = lr * hr - li * hi + cr;
        float ni = lr * hi + li * hr + ci;
        hr = nr; hi = ni;
    }
}

// pass 3: recompute local scan with carry-in, write h (bf16, in-place over Bu) + tail (planar)
__global__ void scan3_kernel(bh* __restrict__ Bu, const float* __restrict__ lamRe,
                             const float* __restrict__ lamIm, const float* __restrict__ iniRe,
                             const float* __restrict__ iniIm, float* __restrict__ outTail,
                             int tailN) {
    int b = blockIdx.x >> 7, c = blockIdx.x & (CHUNKS - 1);
    int n = threadIdx.x;
    float lr = lamRe[n], li = lamIm[n];
    size_t idx = (size_t)blockIdx.x * 256 + n;
    float hr = iniRe[idx], hi = iniIm[idx];
    bh* p = Bu + ((size_t)(b * SEQL + c * CHUNKLN)) * 512;
    for (int i = 0; i < CHUNKLN; ++i) {
        float br = (float)p[n], bi = (float)p[n + 256];
        float nr = lr * hr - li * hi + br;
        float ni = lr * hi + li * hr + bi;
        hr = nr; hi = ni;
        p[n] = (bh)hr; p[n + 256] = (bh)hi;
        p += 512;
    }
    if (c == CHUNKS - 1) {                 // h[:, L-1]
        if (tailN >= 4096) {               // planar: all re, then all im
            outTail[b * 256 + n]        = hr;
            outTail[2048 + b * 256 + n] = hi;
        } else {
            outTail[b * 256 + n] = hr;
        }
    }
}

// ---------------- launch ----------------
extern "C" void kernel_launch(void* const* d_in, const int* in_sizes, int n_in,
                              void* d_out, int out_size, void* d_ws, size_t ws_size,
                              hipStream_t stream) {
    const float* x        = (const float*)d_in[0];
    const float* W        = (const float*)d_in[1];
    const float* bvec     = (const float*)d_in[2];
    const float* nu_log   = (const float*)d_in[3];
    const float* theta_lg = (const float*)d_in[4];
    const float* gamma_lg = (const float*)d_in[5];
    const float* Bre      = (const float*)d_in[6];
    const float* Bim      = (const float*)d_in[7];
    const float* Cre      = (const float*)d_in[8];
    const float* Cim      = (const float*)d_in[9];
    const float* Dvec     = (const float*)d_in[10];

    char* ws = (char*)d_ws;
    bh* xh   = (bh*)(ws);                                   // 64 MB
    bh* bu   = (bh*)(ws + 67108864);                        // 64 MB (becomes h in-place)
    bh* wbt  = (bh*)(ws + 134217728);                       // 512 KB
    bh* wct  = (bh*)(ws + 134217728 + 524288);              // 1 MB
    float* Wt = (float*)(ws + 134217728 + 524288 + 1048576); // 1 MB
    float* sm = (float*)(ws + 134217728 + 524288 + 1048576 + 1048576);
    float* bB = sm;               // 512
    float* bD = sm + 512;         // 512
    float* lamRe  = sm + 1024;    // 256
    float* lamIm  = sm + 1280;
    float* lamSRe = sm + 1536;
    float* lamSIm = sm + 1792;
    float* gamma  = sm + 2048;    // 256
    float* carRe  = sm + 2304;                 // 8*128*256 each
    float* carIm  = carRe + (size_t)BATCH * CHUNKS * 256;
    float* iniRe  = carIm + (size_t)BATCH * CHUNKS * 256;
    float* iniIm  = iniRe + (size_t)BATCH * CHUNKS * 256;

    float* outF    = (float*)d_out;
    float* outTail = outF + (size_t)MTOT * DOUTD;
    int tailN = out_size - MTOT * DOUTD;       // 4096 (float view) or 2048

    conv_x_kernel<<<16384, 256, 0, stream>>>((const float4*)x, xh);
    prep0_kernel<<<1, 512, 0, stream>>>(nu_log, theta_lg, gamma_lg, Bre, Bim, bvec, Dvec,
                                        lamRe, lamIm, lamSRe, lamSIm, gamma, bB, bD);
    transposeW_kernel<<<64, 256, 0, stream>>>(W, Wt);
    prepWB_kernel<<<128, 256, 0, stream>>>(Wt, Bre, Bim, gamma, wbt);
    prepWC_kernel<<<2048, 256, 0, stream>>>(Cre, Cim, Wt, Dvec, wct);

    gemm_kernel<512, false, false><<<512, 512, 0, stream>>>(xh, nullptr, wbt, bB, nullptr, bu);

    scan1_kernel<<<BATCH * CHUNKS, 256, 0, stream>>>(bu, lamRe, lamIm, carRe, carIm);
    scan2_kernel<<<BATCH, 256, 0, stream>>>(carRe, carIm, lamSRe, lamSIm, iniRe, iniIm);
    scan3_kernel<<<BATCH * CHUNKS, 256, 0, stream>>>(bu, lamRe, lamIm, iniRe, iniIm, outTail, tailN);

    gemm_kernel<1024, true, true><<<512, 512, 0, stream>>>(bu, xh, wct, bD, outF, nullptr);
}